// Round 9
// baseline (215.668 us; speedup 1.0000x reference)
//
#include <hip/hip_runtime.h>
#include <hip/hip_bf16.h>

#define B_ 4
#define T_ 4096
#define C_ 1024
#define H_ 128
#define SEG_ 8   // K-tiles per segment (8*64=512 keys)

typedef __attribute__((ext_vector_type(8))) short short8;
typedef __attribute__((ext_vector_type(4))) float f32x4;
typedef __attribute__((ext_vector_type(4))) unsigned short u16x4;

static __device__ __forceinline__ unsigned short f2bf(float f) {
    union { float f; unsigned u; } v; v.f = f;
    unsigned r = v.u + 0x7FFF + ((v.u >> 16) & 1);
    return (unsigned short)(r >> 16);
}

// ---------------- W transpose: [C][H] fp32 -> [H][C] bf16 ----------------
__global__ void wt_kernel(const float* __restrict__ Wq, const float* __restrict__ Wk,
                          const float* __restrict__ Wv, unsigned short* __restrict__ Wt) {
    __shared__ float tile[64][65];
    int c0 = blockIdx.x * 64, h0 = blockIdx.y * 64, w = blockIdx.z;
    const float* W = (w == 0) ? Wq : (w == 1) ? Wk : Wv;
    unsigned short* dst = Wt + (size_t)w * H_ * C_;
    int tr = threadIdx.x >> 6, tc = threadIdx.x & 63;
#pragma unroll
    for (int p = 0; p < 16; ++p) {
        int r = p * 4 + tr;
        tile[r][tc] = W[(size_t)(c0 + r) * H_ + h0 + tc];
    }
    __syncthreads();
#pragma unroll
    for (int p = 0; p < 16; ++p) {
        int r = p * 4 + tr; // h index
        dst[(size_t)(h0 + r) * C_ + c0 + tc] = f2bf(tile[tc][r]);
    }
}

// ---------------- Fused QKV projection: x fp32 [16384 x 1024] * W^T[384][1024] ----------------
// Block = 32 rows, computes Q, K, V together. 4 waves, each owns 96 output cols
// (global col in [0,384): w = col/128, h = col%128). W fragments read direct from L2.
__global__ __launch_bounds__(256) void proj_kernel(
        const float* __restrict__ x, const unsigned short* __restrict__ Wt3,
        unsigned short* __restrict__ Q, unsigned short* __restrict__ K,
        unsigned short* __restrict__ Vt) {
    __shared__ unsigned short Xs[32 * 64];  // bf16 x-tile, XOR-swizzled
    int m0 = blockIdx.x * 32;
    int tid = threadIdx.x;
    int lane = tid & 63, wid = tid >> 6;
    int l15 = lane & 15, g = lane >> 4;
    int l7 = l15 & 7;

    f32x4 acc[2][6];
#pragma unroll
    for (int i = 0; i < 2; i++)
#pragma unroll
        for (int j = 0; j < 6; j++) acc[i][j] = (f32x4)0.0f;

    for (int kt = 0; kt < C_ / 64; ++kt) {
        int k0 = kt * 64;
        // stage x tile [32][64] fp32 -> bf16 (exactly 256 short8 chunks)
        {
            int r = tid >> 3, c8 = tid & 7;
            const float* src = x + (size_t)(m0 + r) * C_ + k0 + c8 * 8;
            float4 v0 = *(const float4*)src;
            float4 v1 = *(const float4*)(src + 4);
            union { short8 s; u16x4 h[2]; } pk;
            pk.h[0].x = f2bf(v0.x); pk.h[0].y = f2bf(v0.y);
            pk.h[0].z = f2bf(v0.z); pk.h[0].w = f2bf(v0.w);
            pk.h[1].x = f2bf(v1.x); pk.h[1].y = f2bf(v1.y);
            pk.h[1].z = f2bf(v1.z); pk.h[1].w = f2bf(v1.w);
            *(short8*)&Xs[r * 64 + ((c8 ^ (r & 7)) << 3)] = pk.s;
        }
        __syncthreads();
#pragma unroll
        for (int kf = 0; kf < 2; ++kf) {
            short8 a[2], bv[6];
#pragma unroll
            for (int mt = 0; mt < 2; mt++) {
                int row = mt * 16 + l15;
                a[mt] = *(const short8*)&Xs[row * 64 + (((kf * 4 + g) ^ l7) << 3)];
            }
#pragma unroll
            for (int nt = 0; nt < 6; nt++) {
                int r = wid * 96 + nt * 16 + l15;   // row of W^T concat [384][1024]
                bv[nt] = *(const short8*)(Wt3 + (size_t)r * C_ + k0 + (kf * 4 + g) * 8);
            }
#pragma unroll
            for (int mt = 0; mt < 2; mt++)
#pragma unroll
                for (int nt = 0; nt < 6; nt++)
                    acc[mt][nt] = __builtin_amdgcn_mfma_f32_16x16x32_bf16(a[mt], bv[nt], acc[mt][nt], 0, 0, 0);
        }
        __syncthreads();
    }
    // epilogue
    int b = m0 >> 12;            // 4096 rows per batch
    int tbase = m0 & (T_ - 1);
#pragma unroll
    for (int nt = 0; nt < 6; nt++) {
        int col = wid * 96 + nt * 16 + l15;
        int w = col >> 7, h = col & 127;
#pragma unroll
        for (int mt = 0; mt < 2; mt++) {
            if (w < 2) {
                unsigned short* outp = (w == 0) ? Q : K;
                int row0 = m0 + mt * 16 + g * 4;
#pragma unroll
                for (int ri = 0; ri < 4; ri++)
                    outp[(size_t)(row0 + ri) * H_ + h] = f2bf(acc[mt][nt][ri]);
            } else {
                int t0 = tbase + mt * 16 + g * 4;
                u16x4 o;
                o.x = f2bf(acc[mt][nt][0]); o.y = f2bf(acc[mt][nt][1]);
                o.z = f2bf(acc[mt][nt][2]); o.w = f2bf(acc[mt][nt][3]);
                *(u16x4*)&Vt[(size_t)(b * H_ + h) * T_ + t0] = o;
            }
        }
    }
}

// ---------------- Flash attention (split-K, no-max softmax, swizzled LDS, K/V prefetch) ----------------
// grid (T/64, 8, B). Segment covers k-tiles [seg*SEG_, min(qb, seg*SEG_+SEG_-1)].
__global__ __launch_bounds__(256) void attn_kernel(
        const unsigned short* __restrict__ Q, const unsigned short* __restrict__ K,
        const unsigned short* __restrict__ Vt,
        float* __restrict__ Opart, float* __restrict__ Lpart) {
    int qb = blockIdx.x, seg = blockIdx.y, b = blockIdx.z;
    if (seg * SEG_ > qb) return;
    __shared__ unsigned short KsF[64 * 128];   // XOR-swizzled
    __shared__ unsigned short VsF[128 * 64];   // V^T tile [h][t], XOR-swizzled
    __shared__ unsigned short PsF[4][16 * 64]; // per-wave P tile, XOR-swizzled
    int tid = threadIdx.x, lane = tid & 63, wid = tid >> 6;
    int l15 = lane & 15, g = lane >> 4;
    int l7 = l15 & 7;
    int q0w = qb * 64 + wid * 16;
    const float alpha = 0.08838834764831845f; // 1/sqrt(128)

    short8 aq[4];
#pragma unroll
    for (int kf = 0; kf < 4; kf++)
        aq[kf] = *(const short8*)(Q + (size_t)(b * T_ + q0w + l15) * H_ + kf * 32 + g * 8);

    f32x4 o[8];
#pragma unroll
    for (int i = 0; i < 8; i++) o[i] = (f32x4)0.0f;
    float l_run[4];
#pragma unroll
    for (int ri = 0; ri < 4; ri++) l_run[ri] = 0.f;

    int kt0 = seg * SEG_;
    int kt_end = min(qb, kt0 + SEG_ - 1);

    short8 kreg[4], vreg[4];
#define LOAD_KV(KT) do { int k0_ = (KT) * 64; \
    _Pragma("unroll") \
    for (int p = 0; p < 4; ++p) { int idx = tid + p * 256; \
        kreg[p] = *(const short8*)(K + (size_t)(b * T_ + k0_ + (idx >> 4)) * H_ + (idx & 15) * 8); } \
    _Pragma("unroll") \
    for (int p = 0; p < 4; ++p) { int idx = tid + p * 256; \
        vreg[p] = *(const short8*)(Vt + (size_t)(b * H_ + (idx >> 3)) * T_ + k0_ + (idx & 7) * 8); } \
    } while (0)

    LOAD_KV(kt0);
    for (int kt = kt0; kt <= kt_end; ++kt) {
        int k0 = kt * 64;
        __syncthreads();   // previous iter's LDS reads complete
#pragma unroll
        for (int p = 0; p < 4; ++p) {
            int idx = tid + p * 256;
            int r = idx >> 4;
            *(short8*)&KsF[r * 128 + (((idx & 15) ^ (r & 7)) << 3)] = kreg[p];
        }
#pragma unroll
        for (int p = 0; p < 4; ++p) {
            int idx = tid + p * 256;
            int r = idx >> 3;
            *(short8*)&VsF[r * 64 + (((idx & 7) ^ (r & 7)) << 3)] = vreg[p];
        }
        __syncthreads();   // tiles visible
        if (kt < kt_end) LOAD_KV(kt + 1);  // prefetch overlaps compute

        // S = Q K^T
        f32x4 s[4];
#pragma unroll
        for (int ct = 0; ct < 4; ct++) {
            s[ct] = (f32x4)0.0f;
#pragma unroll
            for (int kf = 0; kf < 4; kf++) {
                int row = ct * 16 + l15;
                short8 bk = *(const short8*)&KsF[row * 128 + (((kf * 4 + g) ^ l7) << 3)];
                s[ct] = __builtin_amdgcn_mfma_f32_16x16x32_bf16(aq[kf], bk, s[ct], 0, 0, 0);
            }
        }
        bool diag = (kt == qb);
        // exp (no max subtraction), accumulate per-lane partial l, pack P (swizzled)
#pragma unroll
        for (int ct = 0; ct < 4; ct++)
#pragma unroll
            for (int ri = 0; ri < 4; ri++) {
                float v = s[ct][ri] * alpha;
                if (diag) {
                    int kkg = k0 + ct * 16 + l15;
                    int qg = q0w + g * 4 + ri;
                    if (kkg > qg) v = -1e30f;
                }
                float p = __expf(v);
                l_run[ri] += p;
                int row = g * 4 + ri;
                PsF[wid][row * 64 + (((2 * ct + (l15 >> 3)) ^ (row & 7)) << 3) + l7] = f2bf(p);
            }

        // O += P V
#pragma unroll
        for (int kf2 = 0; kf2 < 2; kf2++) {
            short8 ap = *(const short8*)&PsF[wid][l15 * 64 + (((kf2 * 4 + g) ^ l7) << 3)];
#pragma unroll
            for (int ht = 0; ht < 8; ht++) {
                int row = ht * 16 + l15;
                short8 bv = *(const short8*)&VsF[row * 64 + (((kf2 * 4 + g) ^ l7) << 3)];
                o[ht] = __builtin_amdgcn_mfma_f32_16x16x32_bf16(ap, bv, o[ht], 0, 0, 0);
            }
        }
    }
#undef LOAD_KV

    // epilogue: reduce l across the 16 lanes of each row group, write partials
    size_t slot = (((size_t)b * (T_ / 64) + qb) * 8 + seg);
    float* Ob = Opart + slot * 64 * 128;
    float* Lb = Lpart + slot * 64;
#pragma unroll
    for (int ri = 0; ri < 4; ri++) {
        float l = l_run[ri];
#pragma unroll
        for (int off = 1; off < 16; off <<= 1)
            l += __shfl_xor(l, off, 64);
        int qrow = wid * 16 + g * 4 + ri;
        Lb[qrow] = l;
#pragma unroll
        for (int ht = 0; ht < 8; ht++)
            Ob[(size_t)qrow * 128 + ht * 16 + l15] = o[ht][ri];
    }
}

// ---------------- Combine: out = (sum_s Opart) / (sum_s Lpart) ----------------
__global__ __launch_bounds__(256) void combine_kernel(
        const float* __restrict__ Opart, const float* __restrict__ Lpart,
        float* __restrict__ out) {
    int qt = blockIdx.x, b = blockIdx.y;
    int nseg = qt / SEG_ + 1;
    int tid = threadIdx.x;
    size_t obase = (((size_t)b * (T_ / 64) + qt) * 8) * 64 * 128;
    size_t lbase = (((size_t)b * (T_ / 64) + qt) * 8) * 64;
    float4* dst = (float4*)(out + ((size_t)b * T_ + qt * 64) * 128);
#pragma unroll
    for (int i = 0; i < 8; ++i) {
        int e4 = tid + i * 256;       // float4 index within 64x128 tile
        int q = e4 >> 5;
        float4 acc = {0.f, 0.f, 0.f, 0.f};
        float lsum = 0.f;
        for (int s = 0; s < nseg; ++s) {
            float4 v = *((const float4*)(Opart + obase + (size_t)s * 64 * 128) + e4);
            acc.x += v.x; acc.y += v.y; acc.z += v.z; acc.w += v.w;
            lsum += Lpart[lbase + s * 64 + q];
        }
        float inv = 1.0f / lsum;
        float4 r = {acc.x * inv, acc.y * inv, acc.z * inv, acc.w * inv};
        dst[e4] = r;
    }
}

extern "C" void kernel_launch(void* const* d_in, const int* in_sizes, int n_in,
                              void* d_out, int out_size, void* d_ws, size_t ws_size,
                              hipStream_t stream) {
    const float* x  = (const float*)d_in[0];
    const float* Wq = (const float*)d_in[1];
    const float* Wk = (const float*)d_in[2];
    const float* Wv = (const float*)d_in[3];
    float* out = (float*)d_out;

    unsigned short* Wt = (unsigned short*)d_ws;              // [3][H][C] bf16   (768KB)
    unsigned short* Qb = Wt + 3 * (size_t)H_ * C_;           // [B][T][H] bf16
    unsigned short* Kb = Qb + (size_t)B_ * T_ * H_;          // [B][T][H] bf16
    unsigned short* Vt = Kb + (size_t)B_ * T_ * H_;          // [B][H][T] bf16
    float* Opart = (float*)(Vt + (size_t)B_ * T_ * H_);      // [B][64][8][64][128] f32 (67MB)
    float* Lpart = Opart + (size_t)B_ * 64 * 8 * 64 * 128;   // [B][64][8][64] f32

    wt_kernel<<<dim3(C_ / 64, H_ / 64, 3), 256, 0, stream>>>(Wq, Wk, Wv, Wt);
    proj_kernel<<<dim3((B_ * T_) / 32), 256, 0, stream>>>(x, Wt, Qb, Kb, Vt);
    attn_kernel<<<dim3(T_ / 64, 8, B_), 256, 0, stream>>>(Qb, Kb, Vt, Opart, Lpart);
    combine_kernel<<<dim3(T_ / 64, B_), 256, 0, stream>>>(Opart, Lpart, out);
}

// Round 12
// 186.046 us; speedup vs baseline: 1.1592x; 1.1592x over previous
//
#include <hip/hip_runtime.h>
#include <hip/hip_bf16.h>

#define B_ 4
#define T_ 4096
#define C_ 1024
#define H_ 128
#define SEG_ 8   // K-tiles per segment (8*64=512 keys)

typedef __attribute__((ext_vector_type(8))) short short8;
typedef __attribute__((ext_vector_type(4))) float f32x4;
typedef __attribute__((ext_vector_type(4))) unsigned short u16x4;

static __device__ __forceinline__ unsigned short f2bf(float f) {
    union { float f; unsigned u; } v; v.f = f;
    unsigned r = v.u + 0x7FFF + ((v.u >> 16) & 1);
    return (unsigned short)(r >> 16);
}

// ---------------- W transpose: [C][H] fp32 -> [H][C] bf16 ----------------
__global__ void wt_kernel(const float* __restrict__ Wq, const float* __restrict__ Wk,
                          const float* __restrict__ Wv, unsigned short* __restrict__ Wt) {
    __shared__ float tile[64][65];
    int c0 = blockIdx.x * 64, h0 = blockIdx.y * 64, w = blockIdx.z;
    const float* W = (w == 0) ? Wq : (w == 1) ? Wk : Wv;
    unsigned short* dst = Wt + (size_t)w * H_ * C_;
    int tr = threadIdx.x >> 6, tc = threadIdx.x & 63;
#pragma unroll
    for (int p = 0; p < 16; ++p) {
        int r = p * 4 + tr;
        tile[r][tc] = W[(size_t)(c0 + r) * H_ + h0 + tc];
    }
    __syncthreads();
#pragma unroll
    for (int p = 0; p < 16; ++p) {
        int r = p * 4 + tr; // h index
        dst[(size_t)(h0 + r) * C_ + c0 + tc] = f2bf(tile[tc][r]);
    }
}

// ---------------- Fused QKV projection v4: LDS-staged, double-buffered ----------------
// Grid 256 blocks (M/64). Block: 64 rows x all 384 cols. 4 waves = 2M x 2N.
// Per kt (K-step 64): stage x[64x64] fp32->bf16 and W^T-chunk [384x64] bf16 in LDS.
__global__ __launch_bounds__(256, 1) void proj_kernel(
        const float* __restrict__ x, const unsigned short* __restrict__ Wt3,
        unsigned short* __restrict__ Q, unsigned short* __restrict__ K,
        unsigned short* __restrict__ Vt) {
    __shared__ unsigned short Xs[2][64 * 64];    // 2 x 8 KB, XOR-swizzled
    __shared__ unsigned short Wsh[2][384 * 64];  // 2 x 48 KB, XOR-swizzled
    int m0 = blockIdx.x * 64;
    int tid = threadIdx.x;
    int lane = tid & 63, wid = tid >> 6;
    int mw = wid >> 1, nw = wid & 1;             // 2M x 2N wave grid
    int l15 = lane & 15, g = lane >> 4;
    int l7 = l15 & 7;

    f32x4 acc[2][12];
#pragma unroll
    for (int i = 0; i < 2; i++)
#pragma unroll
        for (int j = 0; j < 12; j++) acc[i][j] = (f32x4)0.0f;

    float4 xreg[2][2];
    short8 wreg[12];

#define PROJ_LOAD(KT) do { int k0_ = (KT) * 64; \
    _Pragma("unroll") \
    for (int p = 0; p < 2; ++p) { \
        int idx = tid + p * 256; int r = idx >> 3, cg = idx & 7; \
        const float* src = x + (size_t)(m0 + r) * C_ + k0_ + cg * 8; \
        xreg[p][0] = *(const float4*)src; xreg[p][1] = *(const float4*)(src + 4); } \
    _Pragma("unroll") \
    for (int p = 0; p < 12; ++p) { \
        int idx = tid + p * 256; int r = idx >> 3, cg = idx & 7; \
        wreg[p] = *(const short8*)(Wt3 + (size_t)r * C_ + k0_ + cg * 8); } \
    } while (0)

#define PROJ_WRITE(BUF) do { \
    _Pragma("unroll") \
    for (int p = 0; p < 2; ++p) { \
        int idx = tid + p * 256; int r = idx >> 3, cg = idx & 7; \
        union { short8 s; u16x4 h[2]; } pk; \
        pk.h[0].x = f2bf(xreg[p][0].x); pk.h[0].y = f2bf(xreg[p][0].y); \
        pk.h[0].z = f2bf(xreg[p][0].z); pk.h[0].w = f2bf(xreg[p][0].w); \
        pk.h[1].x = f2bf(xreg[p][1].x); pk.h[1].y = f2bf(xreg[p][1].y); \
        pk.h[1].z = f2bf(xreg[p][1].z); pk.h[1].w = f2bf(xreg[p][1].w); \
        *(short8*)&Xs[BUF][r * 64 + ((cg ^ (r & 7)) << 3)] = pk.s; } \
    _Pragma("unroll") \
    for (int p = 0; p < 12; ++p) { \
        int idx = tid + p * 256; int r = idx >> 3, cg = idx & 7; \
        *(short8*)&Wsh[BUF][r * 64 + ((cg ^ (r & 7)) << 3)] = wreg[p]; } \
    } while (0)

    PROJ_LOAD(0);
    PROJ_WRITE(0);
    __syncthreads();

    for (int kt = 0; kt < 16; ++kt) {
        int cur = kt & 1;
        if (kt < 15) PROJ_LOAD(kt + 1);   // issue early; latency hides under MFMA
#pragma unroll
        for (int kf = 0; kf < 2; ++kf) {
            short8 a[2], bv[12];
#pragma unroll
            for (int mt = 0; mt < 2; mt++) {
                int row = mw * 32 + mt * 16 + l15;
                a[mt] = *(const short8*)&Xs[cur][row * 64 + (((kf * 4 + g) ^ (row & 7)) << 3)];
            }
#pragma unroll
            for (int nt = 0; nt < 12; nt++) {
                int row = nw * 192 + nt * 16 + l15;
                bv[nt] = *(const short8*)&Wsh[cur][row * 64 + (((kf * 4 + g) ^ (row & 7)) << 3)];
            }
#pragma unroll
            for (int mt = 0; mt < 2; mt++)
#pragma unroll
                for (int nt = 0; nt < 12; nt++)
                    acc[mt][nt] = __builtin_amdgcn_mfma_f32_16x16x32_bf16(a[mt], bv[nt], acc[mt][nt], 0, 0, 0);
        }
        if (kt < 15) PROJ_WRITE(cur ^ 1);
        __syncthreads();
    }
#undef PROJ_LOAD
#undef PROJ_WRITE

    // epilogue
    int b = m0 >> 12;            // 4096 rows per batch
    int tbase = m0 & (T_ - 1);
#pragma unroll
    for (int nt = 0; nt < 12; nt++) {
        int col = nw * 192 + nt * 16 + l15;
        int w = col >> 7, h = col & 127;
#pragma unroll
        for (int mt = 0; mt < 2; mt++) {
            if (w < 2) {
                unsigned short* outp = (w == 0) ? Q : K;
                int row0 = m0 + mw * 32 + mt * 16 + g * 4;
#pragma unroll
                for (int ri = 0; ri < 4; ri++)
                    outp[(size_t)(row0 + ri) * H_ + h] = f2bf(acc[mt][nt][ri]);
            } else {
                int t0 = tbase + mw * 32 + mt * 16 + g * 4;
                u16x4 o;
                o.x = f2bf(acc[mt][nt][0]); o.y = f2bf(acc[mt][nt][1]);
                o.z = f2bf(acc[mt][nt][2]); o.w = f2bf(acc[mt][nt][3]);
                *(u16x4*)&Vt[(size_t)(b * H_ + h) * T_ + t0] = o;
            }
        }
    }
}

// ---------------- Flash attention (split-K, no-max softmax, swizzled LDS, K/V prefetch) ----------------
// grid (T/64, 8, B). Segment covers k-tiles [seg*SEG_, min(qb, seg*SEG_+SEG_-1)].
__global__ __launch_bounds__(256) void attn_kernel(
        const unsigned short* __restrict__ Q, const unsigned short* __restrict__ K,
        const unsigned short* __restrict__ Vt,
        float* __restrict__ Opart, float* __restrict__ Lpart) {
    int qb = blockIdx.x, seg = blockIdx.y, b = blockIdx.z;
    if (seg * SEG_ > qb) return;
    __shared__ unsigned short KsF[64 * 128];   // XOR-swizzled
    __shared__ unsigned short VsF[128 * 64];   // V^T tile [h][t], XOR-swizzled
    __shared__ unsigned short PsF[4][16 * 64]; // per-wave P tile, XOR-swizzled
    int tid = threadIdx.x, lane = tid & 63, wid = tid >> 6;
    int l15 = lane & 15, g = lane >> 4;
    int l7 = l15 & 7;
    int q0w = qb * 64 + wid * 16;
    const float alpha = 0.08838834764831845f; // 1/sqrt(128)

    short8 aq[4];
#pragma unroll
    for (int kf = 0; kf < 4; kf++)
        aq[kf] = *(const short8*)(Q + (size_t)(b * T_ + q0w + l15) * H_ + kf * 32 + g * 8);

    f32x4 o[8];
#pragma unroll
    for (int i = 0; i < 8; i++) o[i] = (f32x4)0.0f;
    float l_run[4];
#pragma unroll
    for (int ri = 0; ri < 4; ri++) l_run[ri] = 0.f;

    int kt0 = seg * SEG_;
    int kt_end = min(qb, kt0 + SEG_ - 1);

    short8 kreg[4], vreg[4];
#define LOAD_KV(KT) do { int k0_ = (KT) * 64; \
    _Pragma("unroll") \
    for (int p = 0; p < 4; ++p) { int idx = tid + p * 256; \
        kreg[p] = *(const short8*)(K + (size_t)(b * T_ + k0_ + (idx >> 4)) * H_ + (idx & 15) * 8); } \
    _Pragma("unroll") \
    for (int p = 0; p < 4; ++p) { int idx = tid + p * 256; \
        vreg[p] = *(const short8*)(Vt + (size_t)(b * H_ + (idx >> 3)) * T_ + k0_ + (idx & 7) * 8); } \
    } while (0)

    LOAD_KV(kt0);
    for (int kt = kt0; kt <= kt_end; ++kt) {
        int k0 = kt * 64;
        __syncthreads();   // previous iter's LDS reads complete
#pragma unroll
        for (int p = 0; p < 4; ++p) {
            int idx = tid + p * 256;
            int r = idx >> 4;
            *(short8*)&KsF[r * 128 + (((idx & 15) ^ (r & 7)) << 3)] = kreg[p];
        }
#pragma unroll
        for (int p = 0; p < 4; ++p) {
            int idx = tid + p * 256;
            int r = idx >> 3;
            *(short8*)&VsF[r * 64 + (((idx & 7) ^ (r & 7)) << 3)] = vreg[p];
        }
        __syncthreads();   // tiles visible
        if (kt < kt_end) LOAD_KV(kt + 1);  // prefetch overlaps compute

        // S = Q K^T
        f32x4 s[4];
#pragma unroll
        for (int ct = 0; ct < 4; ct++) {
            s[ct] = (f32x4)0.0f;
#pragma unroll
            for (int kf = 0; kf < 4; kf++) {
                int row = ct * 16 + l15;
                short8 bk = *(const short8*)&KsF[row * 128 + (((kf * 4 + g) ^ l7) << 3)];
                s[ct] = __builtin_amdgcn_mfma_f32_16x16x32_bf16(aq[kf], bk, s[ct], 0, 0, 0);
            }
        }
        bool diag = (kt == qb);
        // exp (no max subtraction), accumulate per-lane partial l, pack P (swizzled)
#pragma unroll
        for (int ct = 0; ct < 4; ct++)
#pragma unroll
            for (int ri = 0; ri < 4; ri++) {
                float v = s[ct][ri] * alpha;
                if (diag) {
                    int kkg = k0 + ct * 16 + l15;
                    int qg = q0w + g * 4 + ri;
                    if (kkg > qg) v = -1e30f;
                }
                float p = __expf(v);
                l_run[ri] += p;
                int row = g * 4 + ri;
                PsF[wid][row * 64 + (((2 * ct + (l15 >> 3)) ^ (row & 7)) << 3) + l7] = f2bf(p);
            }

        // O += P V
#pragma unroll
        for (int kf2 = 0; kf2 < 2; kf2++) {
            short8 ap = *(const short8*)&PsF[wid][l15 * 64 + (((kf2 * 4 + g) ^ l7) << 3)];
#pragma unroll
            for (int ht = 0; ht < 8; ht++) {
                int row = ht * 16 + l15;
                short8 bv = *(const short8*)&VsF[row * 64 + (((kf2 * 4 + g) ^ l7) << 3)];
                o[ht] = __builtin_amdgcn_mfma_f32_16x16x32_bf16(ap, bv, o[ht], 0, 0, 0);
            }
        }
    }
#undef LOAD_KV

    // epilogue: reduce l across the 16 lanes of each row group, write partials
    size_t slot = (((size_t)b * (T_ / 64) + qb) * 8 + seg);
    float* Ob = Opart + slot * 64 * 128;
    float* Lb = Lpart + slot * 64;
#pragma unroll
    for (int ri = 0; ri < 4; ri++) {
        float l = l_run[ri];
#pragma unroll
        for (int off = 1; off < 16; off <<= 1)
            l += __shfl_xor(l, off, 64);
        int qrow = wid * 16 + g * 4 + ri;
        Lb[qrow] = l;
#pragma unroll
        for (int ht = 0; ht < 8; ht++)
            Ob[(size_t)qrow * 128 + ht * 16 + l15] = o[ht][ri];
    }
}

// ---------------- Combine: out = (sum_s Opart) / (sum_s Lpart) ----------------
// grid (T/64, B, 2): each block handles 32 q-rows (half a 64-row tile).
__global__ __launch_bounds__(256) void combine_kernel(
        const float* __restrict__ Opart, const float* __restrict__ Lpart,
        float* __restrict__ out) {
    int qt = blockIdx.x, b = blockIdx.y, half = blockIdx.z;
    int nseg = qt / SEG_ + 1;
    int tid = threadIdx.x;
    size_t obase = (((size_t)b * (T_ / 64) + qt) * 8) * 64 * 128 + (size_t)half * 32 * 128;
    size_t lbase = (((size_t)b * (T_ / 64) + qt) * 8) * 64 + half * 32;
    float4* dst = (float4*)(out + ((size_t)b * T_ + qt * 64 + half * 32) * 128);
#pragma unroll
    for (int i = 0; i < 4; ++i) {
        int e4 = tid + i * 256;       // float4 index within 32x128 half-tile
        int q = e4 >> 5;
        float4 acc = {0.f, 0.f, 0.f, 0.f};
        float lsum = 0.f;
        for (int s = 0; s < nseg; ++s) {
            float4 v = *((const float4*)(Opart + obase + (size_t)s * 64 * 128) + e4);
            acc.x += v.x; acc.y += v.y; acc.z += v.z; acc.w += v.w;
            lsum += Lpart[lbase + s * 64 + q];
        }
        float inv = 1.0f / lsum;
        float4 r = {acc.x * inv, acc.y * inv, acc.z * inv, acc.w * inv};
        dst[e4] = r;
    }
}

extern "C" void kernel_launch(void* const* d_in, const int* in_sizes, int n_in,
                              void* d_out, int out_size, void* d_ws, size_t ws_size,
                              hipStream_t stream) {
    const float* x  = (const float*)d_in[0];
    const float* Wq = (const float*)d_in[1];
    const float* Wk = (const float*)d_in[2];
    const float* Wv = (const float*)d_in[3];
    float* out = (float*)d_out;

    unsigned short* Wt = (unsigned short*)d_ws;              // [3][H][C] bf16   (768KB)
    unsigned short* Qb = Wt + 3 * (size_t)H_ * C_;           // [B][T][H] bf16
    unsigned short* Kb = Qb + (size_t)B_ * T_ * H_;          // [B][T][H] bf16
    unsigned short* Vt = Kb + (size_t)B_ * T_ * H_;          // [B][H][T] bf16
    float* Opart = (float*)(Vt + (size_t)B_ * T_ * H_);      // [B][64][8][64][128] f32 (67MB)
    float* Lpart = Opart + (size_t)B_ * 64 * 8 * 64 * 128;   // [B][64][8][64] f32

    wt_kernel<<<dim3(C_ / 64, H_ / 64, 3), 256, 0, stream>>>(Wq, Wk, Wv, Wt);
    proj_kernel<<<dim3((B_ * T_) / 64), 256, 0, stream>>>(x, Wt, Qb, Kb, Vt);
    attn_kernel<<<dim3(T_ / 64, 8, B_), 256, 0, stream>>>(Qb, Kb, Vt, Opart, Lpart);
    combine_kernel<<<dim3(T_ / 64, B_, 2), 256, 0, stream>>>(Opart, Lpart, out);
}